// Round 4
// baseline (177.438 us; speedup 1.0000x reference)
//
#include <hip/hip_runtime.h>

#define BATCH 16
#define HH 512
#define WW 512
#define NPIX (BATCH * HH * WW)

#define RAD 4
#define OT 32              // output tile (32x32)
#define MT (OT + 2*RAD)    // 40: m/t intermediate tile
#define ST (MT + 2*RAD)    // 48: s/q input tile

// ---------------------------------------------------------------------------
// Fused kernel: per 32x32 output tile
//   phase 0: normalize filter (per-block, cheap), load s=SUM_c x, q=SUM_c x^2
//            on the 48x48 halo tile (zero-padded SAME)
//   phase 1: m = conv(s,f) on 40x40 region; t = q - 2ms + 3m^2 in LDS
//            (t forced to 0 outside the image); write m for inner 32x32
//   phase 2: sigma = sqrt(conv(t,f)) on 32x32; write sigma + block partial sum
// ---------------------------------------------------------------------------
__global__ __launch_bounds__(256) void lcn_fused_kernel(
        const float* __restrict__ x, const float* __restrict__ filt,
        float* __restrict__ m, float* __restrict__ sig,
        float* __restrict__ partial) {
    __shared__ float s48[ST][ST];
    __shared__ float q48[ST][ST];
    __shared__ float t40[MT][MT];
    __shared__ float fs[81];
    __shared__ float fsum_sh;
    __shared__ float wsum[4];

    const int tid = threadIdx.x;
    const int b = blockIdx.z;
    const int h0 = blockIdx.y * OT;
    const int w0 = blockIdx.x * OT;
    const float* xb = x + (size_t)b * HH * WW * 3;

    // ---- filter sum (wave 0 only): sum(filt + 10) over 81 taps
    if (tid < 64) {
        float v = filt[tid] + 10.0f;
        if (tid < 17) v += filt[tid + 64] + 10.0f;
#pragma unroll
        for (int o = 32; o > 0; o >>= 1) v += __shfl_down(v, o);
        if (tid == 0) fsum_sh = v;
    }

    // ---- cooperative halo load of s and q (zero outside image)
    for (int i = tid; i < ST * ST; i += 256) {
        int r = i / ST, c = i - r * ST;
        int gh = h0 - 2 * RAD + r, gw = w0 - 2 * RAD + c;
        float sv = 0.0f, qv = 0.0f;
        if (gh >= 0 && gh < HH && gw >= 0 && gw < WW) {
            const float* xp = xb + ((size_t)gh * WW + gw) * 3;
            float a0 = xp[0], a1 = xp[1], a2 = xp[2];
            sv = a0 + a1 + a2;
            qv = a0 * a0 + a1 * a1 + a2 * a2;
        }
        s48[r][c] = sv;
        q48[r][c] = qv;
    }
    __syncthreads();

    if (tid < 81) fs[tid] = (filt[tid] + 10.0f) / fsum_sh;
    __syncthreads();

    // ---- phase 1: m over 40x40 via sliding 7-row window; t into LDS
    {
        const int c2 = tid % MT;        // 0..39
        const int g = tid / MT;         // 0..6; g==6 idle
        if (g < 6) {
            const int rbeg = g * 7;
            const int rcnt = (rbeg + 7 <= MT) ? 7 : (MT - rbeg);   // 7 or 5
            float acc[7] = {0.f, 0.f, 0.f, 0.f, 0.f, 0.f, 0.f};
            for (int tr = 0; tr < rcnt + 8; tr++) {
                float v[9];
#pragma unroll
                for (int j = 0; j < 9; j++) v[j] = s48[rbeg + tr][c2 + j];
#pragma unroll
                for (int o = 0; o < 7; o++) {
                    const int dh = tr - o;
                    if (o < rcnt && dh >= 0 && dh < 9) {
                        float a = 0.0f;
#pragma unroll
                        for (int j = 0; j < 9; j++) a += v[j] * fs[dh * 9 + j];
                        acc[o] += a;
                    }
                }
            }
            for (int o = 0; o < rcnt; o++) {
                const int rr = rbeg + o;
                const int gh = h0 - RAD + rr, gw = w0 - RAD + c2;
                const float mv = acc[o];
                const float sc = s48[rr + RAD][c2 + RAD];
                const float qc = q48[rr + RAD][c2 + RAD];
                const bool inimg = (gh >= 0 && gh < HH && gw >= 0 && gw < WW);
                t40[rr][c2] = inimg ? (qc - 2.0f * mv * sc + 3.0f * mv * mv)
                                    : 0.0f;
                if (rr >= RAD && rr < RAD + OT && c2 >= RAD && c2 < RAD + OT) {
                    m[((size_t)b * HH + gh) * WW + gw] = mv;
                }
            }
        }
    }
    __syncthreads();

    // ---- phase 2: sigma over 32x32 via sliding 4-row window
    float psum = 0.0f;
    {
        const int c3 = tid % OT;        // 0..31
        const int g3 = tid / OT;        // 0..7
        const int rbeg = g3 * 4;
        float acc[4] = {0.f, 0.f, 0.f, 0.f};
#pragma unroll
        for (int tr = 0; tr < 12; tr++) {
            float v[9];
#pragma unroll
            for (int j = 0; j < 9; j++) v[j] = t40[rbeg + tr][c3 + j];
#pragma unroll
            for (int o = 0; o < 4; o++) {
                const int dh = tr - o;
                if (dh >= 0 && dh < 9) {
                    float a = 0.0f;
#pragma unroll
                    for (int j = 0; j < 9; j++) a += v[j] * fs[dh * 9 + j];
                    acc[o] += a;
                }
            }
        }
#pragma unroll
        for (int o = 0; o < 4; o++) {
            const float sg = sqrtf(fmaxf(acc[o], 0.0f));
            const int h = h0 + rbeg + o, w = w0 + c3;
            sig[((size_t)b * HH + h) * WW + w] = sg;
            psum += sg;
        }
    }

    // ---- block partial sum (private slot per block; no atomics)
#pragma unroll
    for (int o = 32; o > 0; o >>= 1) psum += __shfl_down(psum, o);
    if ((tid & 63) == 0) wsum[tid >> 6] = psum;
    __syncthreads();
    if (tid == 0)
        partial[b * 256 + blockIdx.y * 16 + blockIdx.x] =
            wsum[0] + wsum[1] + wsum[2] + wsum[3];
}

// ---------------------------------------------------------------------------
// Reduce 256 partials per batch -> bsum[b]
// ---------------------------------------------------------------------------
__global__ __launch_bounds__(256) void reduce_bsum_kernel(
        const float* __restrict__ partial, float* __restrict__ bsum) {
    __shared__ float wsum[4];
    const int b = blockIdx.x, tid = threadIdx.x;
    float v = partial[b * 256 + tid];
#pragma unroll
    for (int o = 32; o > 0; o >>= 1) v += __shfl_down(v, o);
    if ((tid & 63) == 0) wsum[tid >> 6] = v;
    __syncthreads();
    if (tid == 0) bsum[b] = wsum[0] + wsum[1] + wsum[2] + wsum[3];
}

// ---------------------------------------------------------------------------
// Final: out = (x - m) / max(mean_b, sigma); 4 pixels (12 floats) / thread
// ---------------------------------------------------------------------------
__global__ __launch_bounds__(256) void final_kernel(
        const float* __restrict__ x, const float* __restrict__ m,
        const float* __restrict__ sig, const float* __restrict__ bsum,
        float* __restrict__ out) {
    const int i = blockIdx.x * 256 + threadIdx.x;   // group of 4 pixels
    const int b = i >> 16;                          // (i*4) / (512*512)
    const float mean = bsum[b] * (1.0f / (HH * WW));

    float4 mv = ((const float4*)m)[i];
    float4 sv = ((const float4*)sig)[i];
    const float4* xp = (const float4*)x + (size_t)i * 3;
    float4 a = xp[0], bb = xp[1], cc = xp[2];

    float d0 = fmaxf(mean, sv.x);
    float d1 = fmaxf(mean, sv.y);
    float d2 = fmaxf(mean, sv.z);
    float d3 = fmaxf(mean, sv.w);

    float4 o0, o1, o2;
    o0.x = (a.x - mv.x) / d0;
    o0.y = (a.y - mv.x) / d0;
    o0.z = (a.z - mv.x) / d0;
    o0.w = (a.w - mv.y) / d1;
    o1.x = (bb.x - mv.y) / d1;
    o1.y = (bb.y - mv.y) / d1;
    o1.z = (bb.z - mv.z) / d2;
    o1.w = (bb.w - mv.z) / d2;
    o2.x = (cc.x - mv.z) / d2;
    o2.y = (cc.y - mv.w) / d3;
    o2.z = (cc.z - mv.w) / d3;
    o2.w = (cc.w - mv.w) / d3;

    float4* op = (float4*)out + (size_t)i * 3;
    op[0] = o0;
    op[1] = o1;
    op[2] = o2;
}

// ---------------------------------------------------------------------------
extern "C" void kernel_launch(void* const* d_in, const int* in_sizes, int n_in,
                              void* d_out, int out_size, void* d_ws, size_t ws_size,
                              hipStream_t stream) {
    const float* x = (const float*)d_in[0];
    const float* filt = (const float*)d_in[1];
    float* out = (float*)d_out;

    char* ws = (char*)d_ws;
    float* bsum = (float*)(ws + 512);               // 16 floats
    float* partial = (float*)(ws + 1024);           // 4096 floats
    float* m = (float*)(ws + 32768);                // NPIX floats (16.8 MB)
    float* sig = m + NPIX;                          // NPIX floats

    dim3 cgrid(WW / OT, HH / OT, BATCH);            // (16, 16, 16)
    lcn_fused_kernel<<<cgrid, 256, 0, stream>>>(x, filt, m, sig, partial);
    reduce_bsum_kernel<<<BATCH, 256, 0, stream>>>(partial, bsum);
    final_kernel<<<NPIX / 4 / 256, 256, 0, stream>>>(x, m, sig, bsum, out);
}